// Round 14
// baseline (100.941 us; speedup 1.0000x reference)
//
#include <hip/hip_runtime.h>
#include <math.h>

#define PH 7
#define PW 7
#define B_ 4
#define C_ 256
#define H_ 50
#define W_ 50
#define R_ 256
#define S_ (H_ * W_)     // 2500
#define NCELL (PH * PW)  // 49
#define THREADS 512
#define NW (THREADS / 64)   // 8 waves
#define CMP 66              // cm row stride: p*66%32 distinct -> no p-group collision

// Single dispatch, CHW layout, block = (b,c), plane in LDS.
// R11/R13 lesson (counter-backed): lane=cell gathers are LDS-ADDRESS-DIVERGENCE
// bound (49 scattered addrs/ds_read, 5.3M bank conflicts in R12) — instr-count
// fixes don't help. This kernel uses R2's proven-contiguous structure instead:
//   lane = x-column of the roi  -> each row read = CONTIGUOUS ds_read (conflict-
//   free); band boundaries are roi-uniform scalars -> fully scalar loops, no
//   divergence, no per-lane predication (R2's other sin).
// R2 died on 64-line global scatter loads (VMEM-bound, 114 us); from LDS that
// cost vanishes. No atomics, no compaction, one __syncthreads total.
__global__ void __launch_bounds__(THREADS, 8)
roi_pool_band_lds(const float* __restrict__ features, const int* __restrict__ rois,
                  float* __restrict__ out) {
    __shared__ __align__(16) float pl[S_];      // 10.0 KB plane
    __shared__ int4  geom[R_];                  // x1,y1,h,w  (4 KB)
    __shared__ int   gbat[R_];                  // roi batch  (1 KB)
    __shared__ float cmw[NW][PH][CMP];          // per-wave band-col maxes (14.8 KB)

    const int bx   = blockIdx.x;
    const int c    = bx & 255;                  // 0..255
    const int b    = bx >> 8;                   // 0..3
    const int tid  = threadIdx.x;
    const int wid  = tid >> 6;                  // 0..7
    const int lane = tid & 63;

    // decode all rois (no compaction, no atomics)
    if (tid < R_) {
        const int* roi = rois + tid * 5;
        const int x1 = roi[1] >> 4, y1 = roi[2] >> 4;   // floor(v/16)
        gbat[tid] = roi[0];
        geom[tid] = make_int4(x1, y1, (roi[4] >> 4) - y1 + 1, (roi[3] >> 4) - x1 + 1);
    }
    // stage plane (625 float4, coalesced; features read exactly once globally)
    {
        const float4* src = (const float4*)(features + ((size_t)b * C_ + c) * S_);
        float4* dst = (float4*)pl;
        for (int i = tid; i < S_ / 4; i += THREADS) dst[i] = src[i];
    }
    __syncthreads();                            // the only block-wide sync

    // lane -> (p,q) for the reduce phase (lanes 49..63 duplicate, don't store)
    const int lcell = (lane < 48) ? lane : 48;
    const int p = lcell / PW;                   // magic mul
    const int q = lcell - p * PW;

    for (int j = wid; j < R_; j += NW) {
        if (gbat[j] != b) continue;             // wave-uniform skip
        const int4 g = geom[j];
        const int x1S = __builtin_amdgcn_readfirstlane(g.x);
        const int y1S = __builtin_amdgcn_readfirstlane(g.y);
        const int hS  = __builtin_amdgcn_readfirstlane(g.z);
        const int wS  = __builtin_amdgcn_readfirstlane(g.w);

        const int xb = min(x1S + lane, W_ - 1); // clamped col (lanes>=w unused)

        float cm[PH];
        #pragma unroll
        for (int pp = 0; pp < PH; ++pp) cm[pp] = -INFINITY;

        // band loops: ALL bounds scalar (roi-uniform); body = ds_read(contig,
        // conflict-free) + fmax + ptr add. Bands may overlap 1 row (max-safe).
        #pragma unroll
        for (int pp = 0; pp < PH; ++pp) {
            const int sh = y1S + (pp * hS) / PH;
            const int eh = y1S + ((pp + 1) * hS + PH - 1) / PH;
            const float* prow = pl + sh * W_ + xb;
            for (int n = eh - sh; n > 0; --n, prow += W_)
                cm[pp] = fmaxf(cm[pp], *prow);
        }

        // stage cm into this wave's LDS strip (contiguous writes, conflict-free)
        #pragma unroll
        for (int pp = 0; pp < PH; ++pp) cmw[wid][pp][lane] = cm[pp];
        asm volatile("s_waitcnt lgkmcnt(0)" ::: "memory");  // cross-lane RAW
        __builtin_amdgcn_sched_barrier(0);                  // rule-18 fence

        // col reduce: cell (p,q) takes max over its <=9 columns (clamped
        // fixed-trip: duplicates max-safe; bound scalar)
        const int swr  = (q * wS) / PW;                     // per-lane, magic
        const int ewr  = ((q + 1) * wS + PW - 1) / PW;
        const int kwm1 = ewr - swr - 1;                     // >= 0
        const int kwMaxS = wS / PW + 2;                     // scalar bound

        const float* cbase = &cmw[wid][0][0] + p * CMP + swr;
        float m = -INFINITY;
        for (int k = 0; k < kwMaxS; ++k)
            m = fmaxf(m, cbase[min(k, kwm1)]);

        if (lane < NCELL)                       // 49 contiguous floats per roi
            out[((size_t)j * C_ + c) * NCELL + lane] = m;
    }
}

extern "C" void kernel_launch(void* const* d_in, const int* in_sizes, int n_in,
                              void* d_out, int out_size, void* d_ws, size_t ws_size,
                              hipStream_t stream) {
    const float* features = (const float*)d_in[0];
    const int*   rois     = (const int*)d_in[1];
    float*       out      = (float*)d_out;
    (void)d_ws; (void)ws_size;

    roi_pool_band_lds<<<B_ * C_, THREADS, 0, stream>>>(features, rois, out);
}

// Round 15
// 100.158 us; speedup vs baseline: 1.0078x; 1.0078x over previous
//
#include <hip/hip_runtime.h>
#include <math.h>

#define PH 7
#define PW 7
#define B_ 4
#define C_ 256
#define H_ 50
#define W_ 50
#define R_ 256
#define S_ (H_ * W_)     // 2500
#define NCELL (PH * PW)  // 49
#define MAXW 9           // max window width: ceil(50/7)+1
#define THREADS 448      // 7 waves = 7 row-bands of one q-column

// ---------- kernel 1: features (B,C,H,W) -> (B,H,W,C) ----------
__global__ void transpose_chw_hwc(const float* __restrict__ in, float* __restrict__ out) {
    __shared__ float tile[32][33];
    const int b  = blockIdx.z;
    const int s0 = blockIdx.x * 32;
    const int c0 = blockIdx.y * 32;
    const float* inb  = in  + (size_t)b * C_ * S_;
    float*       outb = out + (size_t)b * S_ * C_;
    const int tx = threadIdx.x;
    #pragma unroll
    for (int i = threadIdx.y; i < 32; i += 8) {
        const int s = s0 + tx;
        if (s < S_) tile[i][tx] = inb[(size_t)(c0 + i) * S_ + s];
    }
    __syncthreads();
    #pragma unroll
    for (int i = threadIdx.y; i < 32; i += 8) {
        const int s = s0 + i;
        if (s < S_) outb[(size_t)s * C_ + (c0 + tx)] = tile[tx][i];
    }
}

__device__ __forceinline__ float4 max4(float4 a, float4 b) {
    a.x = fmaxf(a.x, b.x); a.y = fmaxf(a.y, b.y);
    a.z = fmaxf(a.z, b.z); a.w = fmaxf(a.w, b.w);
    return a;
}

// ---------- kernel 2 (fused pool + output write): block = (roi, q-col) ----
// R10's fusion lost ~15 us to barrier imbalance: its waves were col-cells
// with kw in 1..9 (2x spread). Here the 7 waves of a block are the 7 ROW-
// BANDS of one q-column: band heights differ by at most 1 row and all waves
// share kw -> intra-block imbalance ~6%. Inner loop = the measured-9.2us
// R3-K2 loop verbatim (float4/lane, 1 KB coalesced, 2 rows in flight).
// 1792 blocks (7 rounds/CU) amortize cross-block kw variance.
// Write: LDS [c][p] stage (stride-1 readout), stores at c*49+p*7+q — 4 B @
// 28 B stride, lines co-filled by the 6 sibling q-blocks of the same roi
// (adjacent blockIdx -> same XCD L2 write-combine).
__global__ void __launch_bounds__(THREADS, 4)
roi_pool_qcol(const float* __restrict__ ft, const int* __restrict__ rois,
              float* __restrict__ out) {
    __shared__ float lds[C_ * PH];        // [c][p] at c*7+p, 7168 B
    const int bx   = blockIdx.x;
    const int r    = bx / PW;             // 0..255 (magic mul)
    const int q    = bx - r * PW;         // 0..6 (column window, block-uniform)
    const int p    = threadIdx.x >> 6;    // 0..6 (wave id = row band)
    const int lane = threadIdx.x & 63;

    const int* roi = rois + r * 5;
    const int b  = roi[0];
    const int x1 = roi[1] >> 4;   // floor(v/16), v >= 0
    const int y1 = roi[2] >> 4;
    const int x2 = roi[3] >> 4;
    const int y2 = roi[4] >> 4;
    const int h = y2 - y1 + 1;
    const int w = x2 - x1 + 1;

    const int sh = y1 + (p * h) / PH;
    const int eh = y1 + ((p + 1) * h + PH - 1) / PH;   // height: +-1 across waves
    const int sw = x1 + (q * w) / PW;
    const int ew = x1 + ((q + 1) * w + PW - 1) / PW;
    const int kw = ew - sw;               // 1..9, SAME for all waves in block

    const float* fb = ft + (size_t)b * S_ * C_ + 4 * lane;

    float4 acc = make_float4(-INFINITY, -INFINITY, -INFINITY, -INFINITY);

    int y = sh;
    if ((eh - sh) & 1) {                  // odd band height: single-row prologue
        const float* p0 = fb + (size_t)(y * W_ + sw) * C_;
        float4 v0[MAXW];
        #pragma unroll
        for (int k = 0; k < MAXW; ++k)
            if (k < kw) v0[k] = *(const float4*)(p0 + (size_t)k * C_);
        #pragma unroll
        for (int k = 0; k < MAXW; ++k)
            if (k < kw) acc = max4(acc, v0[k]);
        ++y;
    }
    for (; y < eh; y += 2) {              // even remainder: true row pairs
        const float* p0 = fb + (size_t)( y      * W_ + sw) * C_;
        const float* p1 = fb + (size_t)((y + 1) * W_ + sw) * C_;
        float4 v0[MAXW], v1[MAXW];
        #pragma unroll
        for (int k = 0; k < MAXW; ++k) {
            if (k < kw) {                 // wave-uniform branch
                v0[k] = *(const float4*)(p0 + (size_t)k * C_);
                v1[k] = *(const float4*)(p1 + (size_t)k * C_);
            }
        }
        #pragma unroll
        for (int k = 0; k < MAXW; ++k) {
            if (k < kw) acc = max4(acc, max4(v0[k], v1[k]));
        }
    }

    // stage: lds[c*7 + p], c = 4*lane+j (4 ds_writes/wave; stride-28 aliasing
    // ~8-way on a handful of instructions: negligible)
    lds[(4 * lane + 0) * PH + p] = acc.x;
    lds[(4 * lane + 1) * PH + p] = acc.y;
    lds[(4 * lane + 2) * PH + p] = acc.z;
    lds[(4 * lane + 3) * PH + p] = acc.w;

    __syncthreads();                      // waves arrive within ~1 row of work

    // out (R,C,49): this block owns cells {p*7+q : p=0..6} for all 256 ch.
    // idx = c*7+p -> LDS read stride-1 (conflict-free); global stores 4 B at
    // 28 B stride (sibling q-blocks co-fill the lines in L2).
    float* dst = out + (size_t)r * C_ * NCELL + q;
    #pragma unroll
    for (int idx = threadIdx.x; idx < C_ * PH; idx += THREADS) {
        const int c = idx / PH;           // magic mul
        const int pp = idx - c * PH;
        dst[(size_t)c * NCELL + pp * PW] = lds[idx];
    }
}

extern "C" void kernel_launch(void* const* d_in, const int* in_sizes, int n_in,
                              void* d_out, int out_size, void* d_ws, size_t ws_size,
                              hipStream_t stream) {
    const float* features = (const float*)d_in[0];
    const int*   rois     = (const int*)d_in[1];
    float*       out      = (float*)d_out;

    float* ft = (float*)d_ws;                        // 10.24 MB (ws is 256 MB)

    dim3 tgrid((S_ + 31) / 32, C_ / 32, B_);
    transpose_chw_hwc<<<tgrid, dim3(32, 8), 0, stream>>>(features, ft);
    roi_pool_qcol<<<R_ * PW, THREADS, 0, stream>>>(ft, rois, out);
}

// Round 16
// 92.220 us; speedup vs baseline: 1.0946x; 1.0861x over previous
//
#include <hip/hip_runtime.h>
#include <math.h>

#define PH 7
#define PW 7
#define B_ 4
#define C_ 256
#define H_ 50
#define W_ 50
#define R_ 256
#define S_ (H_ * W_)     // 2500
#define NCELL (PH * PW)  // 49

// SINGLE dispatch, direct from (B,C,H,W) — no transpose, no workspace.
// This is R2's structure with the instruction fat removed (R2: 114 us,
// VALUBusy 49%, loads NOT the limiter at 0.05 loads/cy/CU — the ~15 VALU
// instr/row of per-lane predication + 7 band tests were).
// Wave = (channel, roi); lane = x-column of the roi (clamped to x2 —
// duplicate reads are max-safe, same cache line, NO exec-mask predication).
// Roi geometry is wave-uniform -> band loops have SCALAR bounds; body =
// 1 coalesced global load (<=200 B contiguous) + fmax + pointer add.
// Column reduce via per-wave-private LDS strip (no block barrier needed);
// output = 49 contiguous floats per wave (196 B segments).
// Block = (roi, 4-ch group): 16384 blocks = 64 rounds/CU -> roi-size
// variance fully amortized across the grid.
__global__ void __launch_bounds__(256, 8)
roi_pool_direct(const float* __restrict__ features, const int* __restrict__ rois,
                float* __restrict__ out) {
    __shared__ float cmw[4][PH * 64];     // per-wave strips, 7 KB
    const int bx   = blockIdx.x;
    const int r    = bx >> 6;             // 0..255
    const int cg   = bx & 63;             // 0..63
    const int wid  = threadIdx.x >> 6;    // 0..3
    const int lane = threadIdx.x & 63;
    const int c    = (cg << 2) | wid;     // 0..255

    const int* roi = rois + r * 5;        // r wave-uniform -> scalar loads
    const int b  = roi[0];
    const int x1 = roi[1] >> 4;           // floor(v/16), v in [0,800)
    const int y1 = roi[2] >> 4;
    const int x2 = roi[3] >> 4;
    const int y2 = roi[4] >> 4;
    const int h = y2 - y1 + 1;            // 1..50
    const int w = x2 - x1 + 1;            // 1..50

    const float* plane = features + ((size_t)b * C_ + c) * S_;
    const int xcol = min(x1 + lane, x2);  // clamped col; dup lanes max-safe

    float cm[PH];
    #pragma unroll
    for (int p = 0; p < PH; ++p) cm[p] = -INFINITY;

    // 7 band loops, ALL bounds scalar (wave-uniform); ~4 instr per row.
    // 2 rows in flight per iteration (independent loads).
    #pragma unroll
    for (int p = 0; p < PH; ++p) {
        const int sh = y1 + (p * h) / PH;
        const int eh = y1 + ((p + 1) * h + PH - 1) / PH;   // > sh always
        const float* prow = plane + sh * W_ + xcol;
        int n = eh - sh;
        if (n & 1) {                       // odd height: single-row prologue
            cm[p] = fmaxf(cm[p], *prow);
            prow += W_; --n;
        }
        for (; n > 0; n -= 2, prow += 2 * W_) {
            const float a0 = prow[0];      // two independent loads in flight
            const float a1 = prow[W_];
            cm[p] = fmaxf(cm[p], fmaxf(a0, a1));
        }
    }

    // stage per-wave strip (wave-private -> no block barrier)
    #pragma unroll
    for (int p = 0; p < PH; ++p) cmw[wid][p * 64 + lane] = cm[p];
    asm volatile("s_waitcnt lgkmcnt(0)" ::: "memory");   // cross-lane RAW
    __builtin_amdgcn_sched_barrier(0);                   // rule-18 fence

    // cell (p,q) = max over its <=9 columns; clamped fixed-trip loop with
    // scalar bound (w/7+2) -> no divergence machinery; dup reads max-safe.
    if (lane < NCELL) {
        const int p = lane / PW;                    // magic mul
        const int q = lane - p * PW;
        const int swr  = (q * w) / PW;
        const int ewr  = ((q + 1) * w + PW - 1) / PW;
        const int kwm1 = ewr - swr - 1;             // >= 0
        const int kwMax = w / PW + 2;               // scalar bound
        const float* cbase = &cmw[wid][p * 64 + swr];
        float m = -INFINITY;
        for (int k = 0; k < kwMax; ++k)
            m = fmaxf(m, cbase[min(k, kwm1)]);
        out[((size_t)r * C_ + c) * NCELL + lane] = m;   // 196 B contig/wave
    }
}

extern "C" void kernel_launch(void* const* d_in, const int* in_sizes, int n_in,
                              void* d_out, int out_size, void* d_ws, size_t ws_size,
                              hipStream_t stream) {
    const float* features = (const float*)d_in[0];
    const int*   rois     = (const int*)d_in[1];
    float*       out      = (float*)d_out;
    (void)d_ws; (void)ws_size;

    roi_pool_direct<<<R_ * 64, 256, 0, stream>>>(features, rois, out);
}

// Round 17
// 83.007 us; speedup vs baseline: 1.2161x; 1.1110x over previous
//
#include <hip/hip_runtime.h>
#include <math.h>

#define PH 7
#define PW 7
#define B_ 4
#define C_ 256
#define H_ 50
#define W_ 50
#define R_ 256
#define S_ (H_ * W_)     // 2500
#define NCELL (PH * PW)  // 49

// SINGLE dispatch, direct from (B,C,H,W). Evolution of R16 (measured 40.4 us)
// with the padding-lane waste removed. R16 read 256 B/row (64 cols) while
// E[w]~18: for w<=32 (87% of rois, order-statistics of the roi distribution)
// HALF the bytes were padding. Here each wave owns a channel PAIR:
//   fast path (w<=32): lane=(hc,col) -> one row-load = 32 cols x 2 planes
//     (two 128 B coalesced segments) -> traffic halved for 87% of rois.
//   slow path (w>32):  R16's proven full-width loop, run for c then c+1.
// All R16-proven machinery kept: scalar band bounds (roi geometry wave-
// uniform), clamped dup columns (max-safe), wave-private LDS strip (no
// block barrier), 49-contiguous-float stores. 8192 blocks x 4 waves =
// 32 rounds/SIMD -> roi-size variance amortizes.
__global__ void __launch_bounds__(256, 8)
roi_pool_packed(const float* __restrict__ features, const int* __restrict__ rois,
                float* __restrict__ out) {
    __shared__ float strip[4][PH][64];    // wave-private strips, 7168 B
    const int bx   = blockIdx.x;
    const int r    = bx >> 5;             // 0..255
    const int cb   = (bx & 31) << 3;      // channel-group base, 8 ch/block
    const int wid  = threadIdx.x >> 6;    // 0..3
    const int lane = threadIdx.x & 63;
    const int cw   = cb + (wid << 1);     // wave's channel pair {cw, cw+1}

    const int* roi = rois + r * 5;        // r uniform -> scalar loads
    const int b  = roi[0];
    const int x1 = roi[1] >> 4;           // floor(v/16), v in [0,800)
    const int y1 = roi[2] >> 4;
    const int x2 = roi[3] >> 4;
    const int y2 = roi[4] >> 4;
    const int h = y2 - y1 + 1;            // 1..50
    const int w = x2 - x1 + 1;            // 1..50

    // reduce-phase lane mapping (lanes 49..63 idle there)
    const int cell = (lane < NCELL) ? lane : NCELL - 1;
    const int p  = cell / PW;             // magic mul
    const int q  = cell - p * PW;
    const int swr  = (q * w) / PW;                  // cell col-window (rel)
    const int ewr  = ((q + 1) * w + PW - 1) / PW;
    const int kwm1 = ewr - swr - 1;                 // >= 0
    const int kmax = w / PW + 2;                    // scalar bound, covers kw

    if (w <= 32) {
        // ---- fast path: 2 channels per row-load ----
        const int hc  = lane >> 5;                  // 0,1 -> channel cw+hc
        const int col = lane & 31;
        const int xcol = x1 + min(col, w - 1);      // clamped dup, max-safe
        const float* pl = features + ((size_t)b * C_ + cw + hc) * S_;

        float cm[PH];
        #pragma unroll
        for (int pp = 0; pp < PH; ++pp) cm[pp] = -INFINITY;

        #pragma unroll
        for (int pp = 0; pp < PH; ++pp) {           // scalar band bounds
            const int sh = y1 + (pp * h) / PH;
            const int eh = y1 + ((pp + 1) * h + PH - 1) / PH;
            const float* prow = pl + sh * W_ + xcol;
            int n = eh - sh;
            if (n & 1) { cm[pp] = fmaxf(cm[pp], *prow); prow += W_; --n; }
            for (; n > 0; n -= 2, prow += 2 * W_)
                cm[pp] = fmaxf(cm[pp], fmaxf(prow[0], prow[W_]));
        }

        #pragma unroll
        for (int pp = 0; pp < PH; ++pp)             // lane-linear: conflict-free
            strip[wid][pp][lane] = cm[pp];          // col64 = hc*32+col
        asm volatile("s_waitcnt lgkmcnt(0)" ::: "memory");
        __builtin_amdgcn_sched_barrier(0);          // rule-18 fence

        #pragma unroll
        for (int hc2 = 0; hc2 < 2; ++hc2) {         // reduce channel cw+hc2
            if (lane < NCELL) {
                const float* cbase = &strip[wid][p][(hc2 << 5) + swr];
                float m = -INFINITY;
                for (int k = 0; k < kmax; ++k)      // scalar bound, clamped
                    m = fmaxf(m, cbase[min(k, kwm1)]);
                out[((size_t)r * C_ + cw + hc2) * NCELL + lane] = m;
            }
        }
    } else {
        // ---- slow path (13% of rois): R16's full-width loop, c then c+1 ----
        const int xcol = x1 + min(lane, w - 1);     // clamped dup, max-safe
        #pragma unroll 1
        for (int hc2 = 0; hc2 < 2; ++hc2) {
            const float* pl = features + ((size_t)b * C_ + cw + hc2) * S_;

            float cm[PH];
            #pragma unroll
            for (int pp = 0; pp < PH; ++pp) cm[pp] = -INFINITY;

            #pragma unroll
            for (int pp = 0; pp < PH; ++pp) {
                const int sh = y1 + (pp * h) / PH;
                const int eh = y1 + ((pp + 1) * h + PH - 1) / PH;
                const float* prow = pl + sh * W_ + xcol;
                int n = eh - sh;
                if (n & 1) { cm[pp] = fmaxf(cm[pp], *prow); prow += W_; --n; }
                for (; n > 0; n -= 2, prow += 2 * W_)
                    cm[pp] = fmaxf(cm[pp], fmaxf(prow[0], prow[W_]));
            }

            #pragma unroll
            for (int pp = 0; pp < PH; ++pp)
                strip[wid][pp][lane] = cm[pp];      // full 64-col strip
            asm volatile("s_waitcnt lgkmcnt(0)" ::: "memory");
            __builtin_amdgcn_sched_barrier(0);

            if (lane < NCELL) {
                const float* cbase = &strip[wid][p][swr];
                float m = -INFINITY;
                for (int k = 0; k < kmax; ++k)
                    m = fmaxf(m, cbase[min(k, kwm1)]);
                out[((size_t)r * C_ + cw + hc2) * NCELL + lane] = m;
            }
            // same-wave DS ordering: next pass's strip writes issue after
            // this pass's reads (in-order DS per wave) -> no barrier needed.
        }
    }
}

extern "C" void kernel_launch(void* const* d_in, const int* in_sizes, int n_in,
                              void* d_out, int out_size, void* d_ws, size_t ws_size,
                              hipStream_t stream) {
    const float* features = (const float*)d_in[0];
    const int*   rois     = (const int*)d_in[1];
    float*       out      = (float*)d_out;
    (void)d_ws; (void)ws_size;

    roi_pool_packed<<<R_ * 32, 256, 0, stream>>>(features, rois, out);
}

// Round 18
// 82.572 us; speedup vs baseline: 1.2225x; 1.0053x over previous
//
#include <hip/hip_runtime.h>
#include <math.h>

#define PH 7
#define PW 7
#define B_ 4
#define C_ 256
#define H_ 50
#define W_ 50
#define R_ 256
#define S_ (H_ * W_)     // 2500
#define NCELL (PH * PW)  // 49

// SINGLE dispatch, direct (B,C,H,W). Evolution of R17 (measured 31.2 us
// kernel): R16->R17 showed the cost is SERIAL BAND-LOOP EXECUTIONS per
// channel, not traffic (clamped lanes dedupe in the coalescer). So: pack
// MORE channels per pass. Wave owns 4 channels; per roi (w wave-uniform):
//   npack=4 (w<=16, ~51% of rois): 1 pass,  16 cols x 4 ch per row-load
//   npack=2 (w<=32, ~36%):         2 passes, 32 cols x 2 ch
//   npack=1 (w>32,  ~13%):         4 passes, 64 cols x 1 ch (R16 loop)
// Per-channel serial steps: 0.44x rows avg (R17: 0.57x). Blocks 8192->4096
// (2 rounds at 8/CU -> balance kept; halved per-block decode overhead).
// Proven machinery unchanged: scalar band bounds, clamped dup cols
// (max-safe), wave-private LDS strip + lgkmcnt/sched_barrier fences,
// 196 B contiguous stores.
__global__ void __launch_bounds__(256, 8)
roi_pool_pack4(const float* __restrict__ features, const int* __restrict__ rois,
               float* __restrict__ out) {
    __shared__ float strip[4][PH][64];    // wave-private strips, 7168 B
    const int bx   = blockIdx.x;
    const int r    = bx >> 4;             // 0..255
    const int wid  = threadIdx.x >> 6;    // 0..3
    const int lane = threadIdx.x & 63;
    const int cw   = ((bx & 15) << 4) | (wid << 2);   // wave's 4-ch base

    const int* roi = rois + r * 5;        // r uniform -> scalar loads
    const int b  = roi[0];
    const int x1 = roi[1] >> 4;           // floor(v/16), v in [0,800)
    const int y1 = roi[2] >> 4;
    const int x2 = roi[3] >> 4;
    const int y2 = roi[4] >> 4;
    const int h = y2 - y1 + 1;            // 1..50
    const int w = x2 - x1 + 1;            // 1..50

    // adaptive packing (all wave-uniform scalars)
    const int npacksh = (w <= 16) ? 2 : (w <= 32) ? 1 : 0;
    const int npack   = 1 << npacksh;     // 4 / 2 / 1 channels per pass
    const int ncolsh  = 6 - npacksh;      // 16 / 32 / 64 cols per channel
    const int ncol    = 1 << ncolsh;
    const int passes  = 4 >> npacksh;     // 1 / 2 / 4

    const int hc   = lane >> ncolsh;      // sub-channel within pass
    const int col  = lane & (ncol - 1);
    const int xcol = x1 + min(col, w - 1);   // clamped dup: max-safe, merged

    // reduce-phase lane mapping (lanes 49..63 idle there)
    const int cell = (lane < NCELL) ? lane : NCELL - 1;
    const int p  = cell / PW;             // magic mul
    const int q  = cell - p * PW;
    const int swr  = (q * w) / PW;
    const int ewr  = ((q + 1) * w + PW - 1) / PW;
    const int kwm1 = ewr - swr - 1;       // >= 0
    const int kmax = w / PW + 2;          // scalar bound, covers all windows

    #pragma unroll 1
    for (int pi = 0; pi < passes; ++pi) {
        const int chb = cw + (pi << npacksh);      // pass channel base
        const float* pl = features + ((size_t)b * C_ + chb + hc) * S_;

        float cm[PH];
        #pragma unroll
        for (int pp = 0; pp < PH; ++pp) cm[pp] = -INFINITY;

        #pragma unroll
        for (int pp = 0; pp < PH; ++pp) {          // scalar band bounds
            const int sh = y1 + (pp * h) / PH;
            const int eh = y1 + ((pp + 1) * h + PH - 1) / PH;
            const float* prow = pl + sh * W_ + xcol;
            int n = eh - sh;
            if (n & 1) { cm[pp] = fmaxf(cm[pp], *prow); prow += W_; --n; }
            for (; n > 0; n -= 2, prow += 2 * W_)
                cm[pp] = fmaxf(cm[pp], fmaxf(prow[0], prow[W_]));
        }

        #pragma unroll
        for (int pp = 0; pp < PH; ++pp)            // lane-linear: conflict-free
            strip[wid][pp][lane] = cm[pp];         // col64 = hc*ncol + col
        asm volatile("s_waitcnt lgkmcnt(0)" ::: "memory");   // cross-lane RAW
        __builtin_amdgcn_sched_barrier(0);         // rule-18 fence

        #pragma unroll
        for (int hc2 = 0; hc2 < 4; ++hc2) {        // reduce pass channels
            if (hc2 < npack && lane < NCELL) {     // wave-uniform + lane mask
                const float* cb2 = &strip[wid][p][(hc2 << ncolsh) + swr];
                float m = -INFINITY;
                for (int k = 0; k < kmax; ++k)     // scalar bound, clamped
                    m = fmaxf(m, cb2[min(k, kwm1)]);
                out[((size_t)r * C_ + chb + hc2) * NCELL + lane] = m;
            }
        }
        // next pass's strip writes must stay after this pass's reads:
        // per-wave DS is in-order; pin the compiler too.
        asm volatile("" ::: "memory");
        __builtin_amdgcn_sched_barrier(0);
    }
}

extern "C" void kernel_launch(void* const* d_in, const int* in_sizes, int n_in,
                              void* d_out, int out_size, void* d_ws, size_t ws_size,
                              hipStream_t stream) {
    const float* features = (const float*)d_in[0];
    const int*   rois     = (const int*)d_in[1];
    float*       out      = (float*)d_out;
    (void)d_ws; (void)ws_size;

    roi_pool_pack4<<<R_ * 16, 256, 0, stream>>>(features, rois, out);
}